// Round 1
// baseline (424.370 us; speedup 1.0000x reference)
//
#include <hip/hip_runtime.h>
#include <hip/hip_bf16.h>

// Joiner: out[b,t,u,v] = (enc[b,t,:]+pred[b,u,:])·W[v,:] + bias[v]
// Decomposition: E = enc·W^T (+bias later), P = pred·W^T; out = E + P + bias.
// B=8, T=200, U=50, D=512, V=1024.

typedef __attribute__((ext_vector_type(8))) short bf16x8;   // 8 bf16 in 4 VGPRs
typedef __attribute__((ext_vector_type(4))) float f32x4;

__device__ __forceinline__ unsigned short f2bf(float f) {
    union { float f; unsigned int u; } x; x.f = f;
    unsigned int u = x.u;
    // round-to-nearest-even truncation to bf16
    unsigned int r = (u + 0x7fffu + ((u >> 16) & 1u)) >> 16;
    return (unsigned short)r;
}

// ---- kernel 1: convert enc(819200) ‖ pred(204800) ‖ W(524288) fp32 -> bf16 ----
// dst layout: A[2000][512] bf16 (enc rows 0..1599, pred rows 1600..1999), then W[1024][512] bf16.
__global__ __launch_bounds__(256) void cvt_kernel(const float* __restrict__ enc,
                                                  const float* __restrict__ pred,
                                                  const float* __restrict__ W,
                                                  unsigned short* __restrict__ dst) {
    int i4 = (blockIdx.x * 256 + threadIdx.x) * 4;   // grid sized exactly: 1512*256*4 = 1,548,288
    const float* src;
    if (i4 < 819200)        src = enc  + i4;
    else if (i4 < 1024000)  src = pred + (i4 - 819200);
    else                    src = W    + (i4 - 1024000);
    float4 f = *(const float4*)src;
    ushort4 o;
    o.x = f2bf(f.x); o.y = f2bf(f.y); o.z = f2bf(f.z); o.w = f2bf(f.w);
    *(ushort4*)(dst + i4) = o;
}

// ---- kernel 2: EP[2000][1024] = A[2000][512] · W^T  (bf16 MFMA, fp32 acc) ----
// Per-wave 16x16 tile; block = 4 waves in 2x2 -> 32x32 tile. Grid (63, 32).
// A-frag: lane holds A[m0+(lane&15)][k0+(lane>>4)*8 + j], j=0..7 (contiguous).
// B-frag: lane holds W[n0+(lane&15)][k0+(lane>>4)*8 + j]  (= B[k][n] of A·B).
// C/D: col = n0+(lane&15), row = m0+(lane>>4)*4+reg.
__global__ __launch_bounds__(256) void gemm_kernel(const unsigned short* __restrict__ A,
                                                   const unsigned short* __restrict__ Wb,
                                                   float* __restrict__ EP) {
    int lane = threadIdx.x & 63;
    int wave = threadIdx.x >> 6;
    int quad = lane >> 4;
    int l16  = lane & 15;
    int m0 = blockIdx.x * 32 + (wave >> 1) * 16;
    int n0 = blockIdx.y * 32 + (wave & 1) * 16;
    int row = m0 + l16; if (row > 1999) row = 1999;   // clamp loads; stores guarded
    const bf16x8* ap = (const bf16x8*)(A  + row * 512        + quad * 8);
    const bf16x8* bp = (const bf16x8*)(Wb + (n0 + l16) * 512 + quad * 8);
    f32x4 acc = {0.f, 0.f, 0.f, 0.f};
#pragma unroll
    for (int kk = 0; kk < 16; ++kk) {  // K = 512 = 16 * 32
        acc = __builtin_amdgcn_mfma_f32_16x16x32_bf16(ap[kk * 4], bp[kk * 4], acc, 0, 0, 0);
    }
    int col = n0 + l16;
#pragma unroll
    for (int i = 0; i < 4; ++i) {
        int r = m0 + quad * 4 + i;
        if (r < 2000) EP[r * 1024 + col] = acc[i];
    }
}

// ---- kernel 3: out[bt][u][v] = E[bt][v] + P[b*50+u][v] + bias[v] ----
// One block per (b,t): E row + bias in registers; 50 coalesced float4 stores/thread.
__global__ __launch_bounds__(256) void bcast_kernel(const float* __restrict__ EP,
                                                    const float* __restrict__ bias,
                                                    float* __restrict__ out) {
    int bt = blockIdx.x;            // 0..1599 ; b = bt / 200
    int b  = bt / 200;
    int v0 = threadIdx.x * 4;
    float4 e  = *(const float4*)(EP + bt * 1024 + v0);
    float4 bi = *(const float4*)(bias + v0);
    e.x += bi.x; e.y += bi.y; e.z += bi.z; e.w += bi.w;
    const float* Pb = EP + (size_t)(2000 - 400 + b * 50) * 1024 + v0;  // P rows start at 1600
    float* ob = out + (size_t)bt * 51200 + v0;
#pragma unroll 5
    for (int u = 0; u < 50; ++u) {
        float4 p = *(const float4*)(Pb + u * 1024);
        float4 r;
        r.x = e.x + p.x; r.y = e.y + p.y; r.z = e.z + p.z; r.w = e.w + p.w;
        *(float4*)(ob + u * 1024) = r;
    }
}

// ---- fallback (only if ws too small): direct fp32 compute, one block per (b,t,u) ----
__global__ __launch_bounds__(256) void fallback_kernel(const float* __restrict__ enc,
                                                       const float* __restrict__ pred,
                                                       const float* __restrict__ W,
                                                       const float* __restrict__ bias,
                                                       float* __restrict__ out) {
    int btu = blockIdx.x;           // 0..79999
    int u  = btu % 50;
    int bt = btu / 50;
    int b  = bt / 200;
    __shared__ float j[512];
    const float* e = enc  + bt * 512;
    const float* p = pred + (b * 50 + u) * 512;
    for (int k = threadIdx.x; k < 512; k += 256) j[k] = e[k] + p[k];
    __syncthreads();
    int v = threadIdx.x * 4;
    float a0 = bias[v], a1 = bias[v + 1], a2 = bias[v + 2], a3 = bias[v + 3];
    for (int k = 0; k < 512; k += 4) {
        float4 jk = *(const float4*)(j + k);
        float4 w0 = *(const float4*)(W + (v + 0) * 512 + k);
        float4 w1 = *(const float4*)(W + (v + 1) * 512 + k);
        float4 w2 = *(const float4*)(W + (v + 2) * 512 + k);
        float4 w3 = *(const float4*)(W + (v + 3) * 512 + k);
        a0 += jk.x * w0.x + jk.y * w0.y + jk.z * w0.z + jk.w * w0.w;
        a1 += jk.x * w1.x + jk.y * w1.y + jk.z * w1.z + jk.w * w1.w;
        a2 += jk.x * w2.x + jk.y * w2.y + jk.z * w2.z + jk.w * w2.w;
        a3 += jk.x * w3.x + jk.y * w3.y + jk.z * w3.z + jk.w * w3.w;
    }
    size_t o = (size_t)btu * 1024 + v;
    out[o] = a0; out[o + 1] = a1; out[o + 2] = a2; out[o + 3] = a3;
}

extern "C" void kernel_launch(void* const* d_in, const int* in_sizes, int n_in,
                              void* d_out, int out_size, void* d_ws, size_t ws_size,
                              hipStream_t stream) {
    const float* enc  = (const float*)d_in[0];
    const float* pred = (const float*)d_in[1];
    const float* W    = (const float*)d_in[2];
    const float* bias = (const float*)d_in[3];
    float* out = (float*)d_out;

    // ws layout: A_bf16 [2000*512] (2,048,000 B) | W_bf16 [1024*512] (1,048,576 B) | EP fp32 [2000*1024] (8,192,000 B)
    const size_t NEED = 2048000u + 1048576u + 8192000u;
    if (ws_size >= NEED) {
        unsigned short* AB = (unsigned short*)d_ws;                       // A then W, contiguous bf16
        float* EP = (float*)((char*)d_ws + 2048000 + 1048576);
        cvt_kernel<<<1512, 256, 0, stream>>>(enc, pred, W, AB);
        gemm_kernel<<<dim3(63, 32), 256, 0, stream>>>(AB, AB + 1024000, EP);
        bcast_kernel<<<1600, 256, 0, stream>>>(EP, bias, out);
    } else {
        fallback_kernel<<<80000, 256, 0, stream>>>(enc, pred, W, bias, out);
    }
}

// Round 3
// 368.490 us; speedup vs baseline: 1.1516x; 1.1516x over previous
//
#include <hip/hip_runtime.h>
#include <hip/hip_bf16.h>

// Joiner: out[b,t,u,v] = (enc[b,t,:]+pred[b,u,:])·W[v,:] + bias[v]
// Decomposition: E = enc·W^T, P = pred·W^T; out = E + P + bias.
// B=8, T=200, U=50, D=512, V=1024.

typedef __attribute__((ext_vector_type(8))) short bf16x8;   // 8 bf16 in 4 VGPRs
typedef __attribute__((ext_vector_type(4))) float f32x4;

__device__ __forceinline__ unsigned short f2bf(float f) {
    union { float f; unsigned int u; } x; x.f = f;
    unsigned int u = x.u;
    unsigned int r = (u + 0x7fffu + ((u >> 16) & 1u)) >> 16;  // RNE
    return (unsigned short)r;
}

// ---- kernel 1: convert enc(819200) ‖ pred(204800) ‖ W(524288) fp32 -> bf16 ----
__global__ __launch_bounds__(256) void cvt_kernel(const float* __restrict__ enc,
                                                  const float* __restrict__ pred,
                                                  const float* __restrict__ W,
                                                  unsigned short* __restrict__ dst) {
    int i4 = (blockIdx.x * 256 + threadIdx.x) * 4;   // 1512*256*4 = 1,548,288 exact
    const float* src;
    if (i4 < 819200)        src = enc  + i4;
    else if (i4 < 1024000)  src = pred + (i4 - 819200);
    else                    src = W    + (i4 - 1024000);
    float4 f = *(const float4*)src;
    ushort4 o;
    o.x = f2bf(f.x); o.y = f2bf(f.y); o.z = f2bf(f.z); o.w = f2bf(f.w);
    *(ushort4*)(dst + i4) = o;
}

// ---- kernel 2: EP[2000][1024] = A[2000][512] · W^T  (bf16 MFMA, fp32 acc) ----
__global__ __launch_bounds__(256) void gemm_kernel(const unsigned short* __restrict__ A,
                                                   const unsigned short* __restrict__ Wb,
                                                   float* __restrict__ EP) {
    int lane = threadIdx.x & 63;
    int wave = threadIdx.x >> 6;
    int quad = lane >> 4;
    int l16  = lane & 15;
    int m0 = blockIdx.x * 32 + (wave >> 1) * 16;
    int n0 = blockIdx.y * 32 + (wave & 1) * 16;
    int row = m0 + l16; if (row > 1999) row = 1999;   // clamp loads; stores guarded
    const bf16x8* ap = (const bf16x8*)(A  + row * 512        + quad * 8);
    const bf16x8* bp = (const bf16x8*)(Wb + (n0 + l16) * 512 + quad * 8);
    f32x4 acc = {0.f, 0.f, 0.f, 0.f};
#pragma unroll
    for (int kk = 0; kk < 16; ++kk) {  // K = 512 = 16 * 32
        acc = __builtin_amdgcn_mfma_f32_16x16x32_bf16(ap[kk * 4], bp[kk * 4], acc, 0, 0, 0);
    }
    int col = n0 + l16;
#pragma unroll
    for (int i = 0; i < 4; ++i) {
        int r = m0 + quad * 4 + i;
        if (r < 2000) EP[r * 1024 + col] = acc[i];
    }
}

// ---- kernel 3: out[bt][u][v] = E[bt][v] + P[b*50+u][v] + bias[v] ----
// One block per (b,t). Nontemporal stores: keep the 327 MB output stream from
// evicting the P rows (re-read 200x per b) out of per-XCD L2.
__global__ __launch_bounds__(256) void bcast_kernel(const float* __restrict__ EP,
                                                    const float* __restrict__ bias,
                                                    float* __restrict__ out) {
    int bt = blockIdx.x;            // 0..1599 ; b = bt / 200
    int b  = bt / 200;
    int v0 = threadIdx.x * 4;
    f32x4 e  = *(const f32x4*)(EP + bt * 1024 + v0);
    f32x4 bi = *(const f32x4*)(bias + v0);
    e += bi;
    const float* Pb = EP + (size_t)(1600 + b * 50) * 1024 + v0;  // P rows at 1600..1999
    float* ob = out + (size_t)bt * 51200 + v0;
#pragma unroll 10
    for (int u = 0; u < 50; ++u) {
        f32x4 p = *(const f32x4*)(Pb + u * 1024);
        f32x4 r = e + p;
        __builtin_nontemporal_store(r, (f32x4*)(ob + u * 1024));
    }
}

// ---- fallback (only if ws too small): direct fp32 compute ----
__global__ __launch_bounds__(256) void fallback_kernel(const float* __restrict__ enc,
                                                       const float* __restrict__ pred,
                                                       const float* __restrict__ W,
                                                       const float* __restrict__ bias,
                                                       float* __restrict__ out) {
    int btu = blockIdx.x;           // 0..79999
    int u  = btu % 50;
    int bt = btu / 50;
    int b  = bt / 200;
    __shared__ float j[512];
    const float* e = enc  + bt * 512;
    const float* p = pred + (b * 50 + u) * 512;
    for (int k = threadIdx.x; k < 512; k += 256) j[k] = e[k] + p[k];
    __syncthreads();
    int v = threadIdx.x * 4;
    float a0 = bias[v], a1 = bias[v + 1], a2 = bias[v + 2], a3 = bias[v + 3];
    for (int k = 0; k < 512; k += 4) {
        float4 jk = *(const float4*)(j + k);
        float4 w0 = *(const float4*)(W + (v + 0) * 512 + k);
        float4 w1 = *(const float4*)(W + (v + 1) * 512 + k);
        float4 w2 = *(const float4*)(W + (v + 2) * 512 + k);
        float4 w3 = *(const float4*)(W + (v + 3) * 512 + k);
        a0 += jk.x * w0.x + jk.y * w0.y + jk.z * w0.z + jk.w * w0.w;
        a1 += jk.x * w1.x + jk.y * w1.y + jk.z * w1.z + jk.w * w1.w;
        a2 += jk.x * w2.x + jk.y * w2.y + jk.z * w2.z + jk.w * w2.w;
        a3 += jk.x * w3.x + jk.y * w3.y + jk.z * w3.z + jk.w * w3.w;
    }
    size_t o = (size_t)btu * 1024 + v;
    out[o] = a0; out[o + 1] = a1; out[o + 2] = a2; out[o + 3] = a3;
}

extern "C" void kernel_launch(void* const* d_in, const int* in_sizes, int n_in,
                              void* d_out, int out_size, void* d_ws, size_t ws_size,
                              hipStream_t stream) {
    const float* enc  = (const float*)d_in[0];
    const float* pred = (const float*)d_in[1];
    const float* W    = (const float*)d_in[2];
    const float* bias = (const float*)d_in[3];
    float* out = (float*)d_out;

    // ws layout: A_bf16 [2000*512] (2,048,000 B) | W_bf16 [1024*512] (1,048,576 B) | EP fp32 [2000*1024] (8,192,000 B)
    const size_t NEED = 2048000u + 1048576u + 8192000u;
    if (ws_size >= NEED) {
        unsigned short* AB = (unsigned short*)d_ws;
        float* EP = (float*)((char*)d_ws + 2048000 + 1048576);
        cvt_kernel<<<1512, 256, 0, stream>>>(enc, pred, W, AB);
        gemm_kernel<<<dim3(63, 32), 256, 0, stream>>>(AB, AB + 1024000, EP);
        bcast_kernel<<<1600, 256, 0, stream>>>(EP, bias, out);
    } else {
        fallback_kernel<<<80000, 256, 0, stream>>>(enc, pred, W, bias, out);
    }
}